// Round 8
// baseline (788.615 us; speedup 1.0000x reference)
//
#include <hip/hip_runtime.h>
#include <hip/hip_bf16.h>
#include <math.h>

#define D 128
#define NND 50000
#define NE 800000
#define NB1 196        // scan blocks: 196*256 = 50176 >= 50000
#define TPITCH 152     // ushort pitch for node transpose tile (304 B = 19*16)

typedef __attribute__((ext_vector_type(8))) short shortx8;
typedef __attribute__((ext_vector_type(4))) float floatx4;

__device__ __forceinline__ float silu_f(float v) {
    return v / (1.0f + __expf(-v));
}
__device__ __forceinline__ unsigned short f2bf(float f) {
    union { float f; unsigned int u; } v; v.f = f;
    unsigned int u = v.u;
    u += 0x7fffu + ((u >> 16) & 1u);   // RNE
    return (unsigned short)(u >> 16);
}
__device__ __forceinline__ void unpk(unsigned int u, float& lo, float& hi) {
    union { unsigned int x; float f; } a, b;
    a.x = u << 16;
    b.x = u & 0xffff0000u;
    lo = a.f; hi = b.f;
}

// ---------------- zero (deg) ----------------
__global__ void zero_kernel(float4* __restrict__ p, int n4) {
    int i = blockIdx.x * blockDim.x + threadIdx.x;
    float4 z = make_float4(0.f, 0.f, 0.f, 0.f);
    for (; i < n4; i += gridDim.x * blockDim.x) p[i] = z;
}

// ---------------- CSR build ----------------
__global__ void hist_kernel(const int* __restrict__ ei, int* __restrict__ deg) {
    int e = blockIdx.x * 256 + threadIdx.x;     // NE = 3125*256 exactly
    atomicAdd(&deg[ei[e]], 1);
}

__global__ void scan1_kernel(const int* __restrict__ deg,
                             int* __restrict__ part, int* __restrict__ bsum) {
    __shared__ int s[256];
    const int tid = threadIdx.x;
    const int i = blockIdx.x * 256 + tid;
    int v = (i < NND) ? deg[i] : 0;
    s[tid] = v;
    __syncthreads();
    #pragma unroll
    for (int off = 1; off < 256; off <<= 1) {
        int t = (tid >= off) ? s[tid - off] : 0;
        __syncthreads();
        s[tid] += t;
        __syncthreads();
    }
    part[i] = s[tid] - v;                        // exclusive
    if (tid == 255) bsum[blockIdx.x] = s[255];
}

__global__ void scan2_kernel(const int* __restrict__ bsum, int* __restrict__ boff) {
    __shared__ int s[256];
    const int tid = threadIdx.x;
    int v = (tid < NB1) ? bsum[tid] : 0;
    s[tid] = v;
    __syncthreads();
    #pragma unroll
    for (int off = 1; off < 256; off <<= 1) {
        int t = (tid >= off) ? s[tid - off] : 0;
        __syncthreads();
        s[tid] += t;
        __syncthreads();
    }
    if (tid < NB1) boff[tid] = s[tid] - v;       // exclusive
}

__global__ void scan3_kernel(const int* __restrict__ part, const int* __restrict__ boff,
                             int* __restrict__ rowptr, int* __restrict__ cursor) {
    int i = blockIdx.x * 256 + threadIdx.x;
    if (i < NND) {
        int v = part[i] + boff[i >> 8];
        rowptr[i] = v;
        cursor[i] = v;
    } else if (i == NND) {
        rowptr[NND] = NE;
    }
}

// scatter col + dist2 into CSR order
__global__ void scatter_kernel(const int* __restrict__ ei, const float* __restrict__ pos,
                               int* __restrict__ cursor,
                               int* __restrict__ ecol, float* __restrict__ ed2) {
    int e = blockIdx.x * 256 + threadIdx.x;     // NE exact multiple of 256
    int r = ei[e], c = ei[NE + e];
    float dx = pos[r * 3 + 0] - pos[c * 3 + 0];
    float dy = pos[r * 3 + 1] - pos[c * 3 + 1];
    float dz = pos[r * 3 + 2] - pos[c * 3 + 2];
    int slot = atomicAdd(&cursor[r], 1);
    ecol[slot] = c;
    ed2[slot] = dx * dx + dy * dy + dz * dz;
}

// ---------------- generic B-fragment weight swizzle ----------------
// Wf flat f = (((ks*4+quad)*128)+n*16+mrow)*8+j  <->  W[k=ks*32+quad*8+j][col=n*16+mrow]
__global__ void wswz_kernel(const float* __restrict__ W,
                            unsigned short* __restrict__ Wf) {
    int f = blockIdx.x * 256 + threadIdx.x;
    int j    = f & 7;
    int mrow = (f >> 3) & 15;
    int n    = (f >> 7) & 7;
    int rest = f >> 10;
    int quad = rest & 3;
    int ks   = rest >> 2;
    int col = n * 16 + mrow;
    int k   = ks * 32 + quad * 8 + j;
    Wf[f] = f2bf(W[k * D + col]);
}

// wlf: bf16 copy of W1e row 256 (dist2 weights), k-order = lane chunk order
__global__ void wlf_kernel(const float* __restrict__ W1e,
                           unsigned short* __restrict__ wlf) {
    int t = threadIdx.x;   // 128 threads
    wlf[t] = f2bf(W1e[256 * D + t]);
}

// ---------------- x -> bf16 ----------------
__global__ void x2bf_kernel(const float4* __restrict__ x4, uint2* __restrict__ xbf) {
    int i = blockIdx.x * 256 + threadIdx.x;   // NND*D/4 = 1.6M exact
    float4 v = x4[i];
    uint2 o;
    o.x = (unsigned int)f2bf(v.x) | ((unsigned int)f2bf(v.y) << 16);
    o.y = (unsigned int)f2bf(v.z) | ((unsigned int)f2bf(v.w) << 16);
    xbf[i] = o;
}

// ---------------- A' = bf16(x@W1e_top + b1e), B = bf16(x@W1e_bot)  [MFMA] ----
__global__ __launch_bounds__(256) void precompute_kernel(
        const unsigned short* __restrict__ xbf,
        const unsigned short* __restrict__ w1f,   // 256x128 swizzled
        const float* __restrict__ b1e,
        unsigned short* __restrict__ A,
        unsigned short* __restrict__ Bm) {
    const int t    = threadIdx.x;
    const int wv   = t >> 6;
    const int lane = t & 63;
    const int mrow = lane & 15;
    const int quad = lane >> 4;
    const int tile = blockIdx.x * 4 + wv;
    if (tile >= 3125) return;
    const int n0 = tile * 16;

    const uint4* xrow = (const uint4*)(xbf + ((size_t)(n0 + mrow) << 7));
    const uint4* wp   = (const uint4*)w1f;

    floatx4 accA[8], accB[8];
    #pragma unroll
    for (int n = 0; n < 8; ++n) {
        accA[n] = (floatx4){0.f, 0.f, 0.f, 0.f};
        accB[n] = (floatx4){0.f, 0.f, 0.f, 0.f};
    }

    #pragma unroll
    for (int s = 0; s < 4; ++s) {
        union { uint4 u; shortx8 v; } af;
        af.u = xrow[s * 4 + quad];
        const int baseA = (s * 4 + quad) * 128 + mrow;
        const int baseB = ((s + 4) * 4 + quad) * 128 + mrow;
        #pragma unroll
        for (int n = 0; n < 8; ++n) {
            union { uint4 u; shortx8 v; } bfA, bfB;
            bfA.u = wp[baseA + n * 16];
            bfB.u = wp[baseB + n * 16];
            accA[n] = __builtin_amdgcn_mfma_f32_16x16x32_bf16(af.v, bfA.v, accA[n], 0, 0, 0);
            accB[n] = __builtin_amdgcn_mfma_f32_16x16x32_bf16(af.v, bfB.v, accB[n], 0, 0, 0);
        }
    }

    float bb[8];
    #pragma unroll
    for (int n = 0; n < 8; ++n) bb[n] = b1e[n * 16 + mrow];

    #pragma unroll
    for (int reg = 0; reg < 4; ++reg) {
        const int node = n0 + quad * 4 + reg;
        #pragma unroll
        for (int n = 0; n < 8; ++n) {
            const int col = n * 16 + mrow;
            A[(size_t)node * D + col]  = f2bf(accA[n][reg] + bb[n]);
            Bm[(size_t)node * D + col] = f2bf(accB[n][reg]);
        }
    }
}

// ---------------- fused edge MLP + per-node aggregation ----------------
// 1 wave = 1 node (block 64). Software-pipelined: tile t+1's meta + B-rows
// issue before tile t's compute. wl reloaded per tile (256 B, L1-hot).
__global__ __launch_bounds__(64, 3) void edgeagg_kernel(
        const unsigned short* __restrict__ Abf,
        const unsigned short* __restrict__ Bbf,
        const int* __restrict__ rowptr,
        const int* __restrict__ ecol,
        const float* __restrict__ ed2,
        const unsigned short* __restrict__ wlf,
        const unsigned short* __restrict__ W2f,
        const float* __restrict__ b2e,
        unsigned short* __restrict__ aggbf) {
    const int lane = threadIdx.x;
    const int mrow = lane & 15;
    const int quad = lane >> 4;
    const int node = blockIdx.x;                 // 50000 blocks

    const int start = rowptr[node];
    const int d     = rowptr[node + 1] - start;

    // hoisted: A' row (packed bf16) + epilogue bias
    const uint4* arow = (const uint4*)(Abf + ((size_t)node << 7));
    uint4 au[4];
    #pragma unroll
    for (int s = 0; s < 4; ++s) au[s] = arow[s * 4 + quad];
    float bias[8];
    #pragma unroll
    for (int k = 0; k < 8; ++k) bias[k] = b2e[k * 16 + mrow];

    float nacc[8];
    #pragma unroll
    for (int k = 0; k < 8; ++k) nacc[k] = 0.f;

    const uint4* w2p = (const uint4*)W2f;
    const uint4* wlq = (const uint4*)wlf;

    // tile-0 meta + B prefetch
    const bool v0 = (mrow < d);
    const int  i0 = start + (v0 ? mrow : 0);
    float d2c = v0 ? ed2[i0] : 0.f;
    {
        // issue c load then B loads (chain unavoidable for tile 0)
    }
    int cc = v0 ? ecol[i0] : 0;
    uint4 bu[4];
    {
        const uint4* br = (const uint4*)(Bbf + ((size_t)cc << 7));
        #pragma unroll
        for (int s = 0; s < 4; ++s) bu[s] = br[s * 4 + quad];
    }

    for (int tb = 0; tb < d; tb += 16) {
        // ---- prefetch next tile (meta + B-rows) ----
        const int  ein = tb + 16 + mrow;
        const bool vn  = ein < d;
        const int  idn = start + (vn ? ein : 0);
        const int  cn  = vn ? ecol[idn] : 0;
        const float d2n = vn ? ed2[idn] : 0.f;
        uint4 bn[4];
        {
            const uint4* br = (const uint4*)(Bbf + ((size_t)cn << 7));
            #pragma unroll
            for (int s = 0; s < 4; ++s) bn[s] = br[s * 4 + quad];
        }

        // ---- compute current tile ----
        floatx4 acc[8];
        #pragma unroll
        for (int k = 0; k < 8; ++k) acc[k] = (floatx4){0.f, 0.f, 0.f, 0.f};

        #pragma unroll
        for (int s = 0; s < 4; ++s) {
            uint4 wlu = wlq[s * 4 + quad];   // L1-hot 256 B array

            float a0, a1, a2, a3, a4, a5, a6, a7;
            float q0, q1, q2, q3, q4, q5, q6, q7;
            float w0, w1, w2, w3, w4, w5, w6, w7;
            unpk(au[s].x, a0, a1); unpk(au[s].y, a2, a3);
            unpk(au[s].z, a4, a5); unpk(au[s].w, a6, a7);
            unpk(bu[s].x, q0, q1); unpk(bu[s].y, q2, q3);
            unpk(bu[s].z, q4, q5); unpk(bu[s].w, q6, q7);
            unpk(wlu.x, w0, w1); unpk(wlu.y, w2, w3);
            unpk(wlu.z, w4, w5); unpk(wlu.w, w6, w7);

            float h0 = silu_f(fmaf(d2c, w0, a0 + q0));
            float h1 = silu_f(fmaf(d2c, w1, a1 + q1));
            float h2 = silu_f(fmaf(d2c, w2, a2 + q2));
            float h3 = silu_f(fmaf(d2c, w3, a3 + q3));
            float h4 = silu_f(fmaf(d2c, w4, a4 + q4));
            float h5 = silu_f(fmaf(d2c, w5, a5 + q5));
            float h6 = silu_f(fmaf(d2c, w6, a6 + q6));
            float h7 = silu_f(fmaf(d2c, w7, a7 + q7));

            union { shortx8 v; __hip_bfloat162 p[4]; } af;
            af.p[0] = __float22bfloat162_rn(float2{h0, h1});
            af.p[1] = __float22bfloat162_rn(float2{h2, h3});
            af.p[2] = __float22bfloat162_rn(float2{h4, h5});
            af.p[3] = __float22bfloat162_rn(float2{h6, h7});

            const int base = (s * 4 + quad) * 128 + mrow;
            #pragma unroll
            for (int k = 0; k < 8; ++k) {
                union { uint4 u; shortx8 v; } bf;
                bf.u = w2p[base + k * 16];
                acc[k] = __builtin_amdgcn_mfma_f32_16x16x32_bf16(af.v, bf.v, acc[k], 0, 0, 0);
            }
        }

        // epilogue: bias + silu, mask pad rows, accumulate
        #pragma unroll
        for (int reg = 0; reg < 4; ++reg) {
            const bool vr = (tb + quad * 4 + reg) < d;
            #pragma unroll
            for (int k = 0; k < 8; ++k)
                nacc[k] += vr ? silu_f(acc[k][reg] + bias[k]) : 0.f;
        }

        // rotate pipeline registers
        d2c = d2n;
        #pragma unroll
        for (int s = 0; s < 4; ++s) bu[s] = bn[s];
    }

    // cross-quad reduction: full column sums
    #pragma unroll
    for (int k = 0; k < 8; ++k) {
        float v = nacc[k];
        v += __shfl_xor(v, 16);
        v += __shfl_xor(v, 32);
        nacc[k] = v;
    }
    const int n8a = quad * 2, n8b = quad * 2 + 1;
    aggbf[(size_t)node * D + n8a * 16 + mrow] = f2bf(nacc[n8a]);
    aggbf[(size_t)node * D + n8b * 16 + mrow] = f2bf(nacc[n8b]);
}

// ---------------- node MLP + residual + LayerNorm  [MFMA] ----------------
__global__ __launch_bounds__(64) void node_kernel(
        const unsigned short* __restrict__ xbf,
        const unsigned short* __restrict__ aggbf,
        const unsigned short* __restrict__ w1nf,  // 256x128 swizzled
        const float* __restrict__ b1n,
        const unsigned short* __restrict__ w2nf,  // 128x128 swizzled
        const float* __restrict__ b2n,
        const float* __restrict__ x,
        const float* __restrict__ gamma,
        const float* __restrict__ beta,
        float* __restrict__ out) {
    __shared__ __align__(16) unsigned short ts[16 * TPITCH];
    const int lane = threadIdx.x;
    const int mrow = lane & 15;
    const int quad = lane >> 4;
    const int n0 = blockIdx.x * 16;      // 3125 blocks exact

    const uint4* xrow = (const uint4*)(xbf + ((size_t)(n0 + mrow) << 7));
    const uint4* grow = (const uint4*)(aggbf + ((size_t)(n0 + mrow) << 7));
    const uint4* w1p  = (const uint4*)w1nf;
    const uint4* w2p  = (const uint4*)w2nf;

    floatx4 acc[8];
    #pragma unroll
    for (int n = 0; n < 8; ++n) {
        float b = b1n[n * 16 + mrow];
        acc[n] = (floatx4){b, b, b, b};
    }

    #pragma unroll
    for (int s = 0; s < 4; ++s) {
        union { uint4 u; shortx8 v; } af;
        af.u = xrow[s * 4 + quad];
        const int base = (s * 4 + quad) * 128 + mrow;
        #pragma unroll
        for (int n = 0; n < 8; ++n) {
            union { uint4 u; shortx8 v; } bf;
            bf.u = w1p[base + n * 16];
            acc[n] = __builtin_amdgcn_mfma_f32_16x16x32_bf16(af.v, bf.v, acc[n], 0, 0, 0);
        }
    }
    #pragma unroll
    for (int s = 0; s < 4; ++s) {
        union { uint4 u; shortx8 v; } af;
        af.u = grow[s * 4 + quad];
        const int base = ((s + 4) * 4 + quad) * 128 + mrow;
        #pragma unroll
        for (int n = 0; n < 8; ++n) {
            union { uint4 u; shortx8 v; } bf;
            bf.u = w1p[base + n * 16];
            acc[n] = __builtin_amdgcn_mfma_f32_16x16x32_bf16(af.v, bf.v, acc[n], 0, 0, 0);
        }
    }

    // silu -> LDS (row-major [m][col], transpose for stage-2 A-frags)
    #pragma unroll
    for (int reg = 0; reg < 4; ++reg) {
        const int m = quad * 4 + reg;
        #pragma unroll
        for (int n = 0; n < 8; ++n)
            ts[m * TPITCH + n * 16 + mrow] = f2bf(silu_f(acc[n][reg]));
    }
    __syncthreads();

    floatx4 acc2[8];
    #pragma unroll
    for (int n = 0; n < 8; ++n) {
        float b = b2n[n * 16 + mrow];
        acc2[n] = (floatx4){b, b, b, b};
    }
    #pragma unroll
    for (int s = 0; s < 4; ++s) {
        shortx8 af2 = *(const shortx8*)((const char*)ts +
                        mrow * (TPITCH * 2) + (s * 4 + quad) * 16);
        const int base = (s * 4 + quad) * 128 + mrow;
        #pragma unroll
        for (int n = 0; n < 8; ++n) {
            union { uint4 u; shortx8 v; } bf;
            bf.u = w2p[base + n * 16];
            acc2[n] = __builtin_amdgcn_mfma_f32_16x16x32_bf16(af2, bf.v, acc2[n], 0, 0, 0);
        }
    }

    float g[8], bt[8];
    #pragma unroll
    for (int n = 0; n < 8; ++n) {
        g[n]  = gamma[n * 16 + mrow];
        bt[n] = beta[n * 16 + mrow];
    }
    #pragma unroll
    for (int reg = 0; reg < 4; ++reg) {
        const int node = n0 + quad * 4 + reg;
        float u[8];
        float s1 = 0.f, s2 = 0.f;
        #pragma unroll
        for (int n = 0; n < 8; ++n) {
            u[n] = acc2[n][reg] + x[(size_t)node * D + n * 16 + mrow];
            s1 += u[n];
            s2 += u[n] * u[n];
        }
        #pragma unroll
        for (int off = 1; off < 16; off <<= 1) {
            s1 += __shfl_xor(s1, off);
            s2 += __shfl_xor(s2, off);
        }
        const float mu  = s1 * (1.f / 128.f);
        const float var = s2 * (1.f / 128.f) - mu * mu;
        const float rs  = rsqrtf(var + 1e-5f);
        #pragma unroll
        for (int n = 0; n < 8; ++n)
            out[(size_t)node * D + n * 16 + mrow] = (u[n] - mu) * rs * g[n] + bt[n];
    }
}

extern "C" void kernel_launch(void* const* d_in, const int* in_sizes, int n_in,
                              void* d_out, int out_size, void* d_ws, size_t ws_size,
                              hipStream_t stream) {
    const float* x     = (const float*)d_in[0];
    const float* pos   = (const float*)d_in[1];
    const int*   ei    = (const int*)d_in[2];
    const float* W1e   = (const float*)d_in[3];
    const float* b1e   = (const float*)d_in[4];
    const float* W2e   = (const float*)d_in[5];
    const float* b2e   = (const float*)d_in[6];
    const float* W1n   = (const float*)d_in[7];
    const float* b1n   = (const float*)d_in[8];
    const float* W2n   = (const float*)d_in[9];
    const float* b2n   = (const float*)d_in[10];
    const float* gamma = (const float*)d_in[11];
    const float* beta  = (const float*)d_in[12];
    float* out = (float*)d_out;

    // ws layout (all offsets 16B-aligned)
    unsigned short* Abf    = (unsigned short*)d_ws;                   // 12.8 MB
    unsigned short* Bbf    = Abf + (size_t)NND * D;                   // 12.8 MB
    unsigned short* aggbf  = Bbf + (size_t)NND * D;                   // 12.8 MB
    unsigned short* xbf    = aggbf + (size_t)NND * D;                 // 12.8 MB
    unsigned short* w1f    = xbf + (size_t)NND * D;                   // 64 KB (256x128)
    unsigned short* w1nf   = w1f + 256 * D;                           // 64 KB (256x128)
    unsigned short* w2f    = w1nf + 256 * D;                          // 32 KB (128x128)
    unsigned short* w2nf   = w2f + D * D;                             // 32 KB (128x128)
    unsigned short* wlf    = w2nf + D * D;                            // 256 B
    int*            deg    = (int*)(wlf + 128);
    int*            part   = deg + 50176;
    int*            bsum   = part + 50176;
    int*            boff   = bsum + 256;
    int*            rowptr = boff + 256;                              // 50004
    int*            cursor = rowptr + 50004;
    int*            ecol   = cursor + 50000;                          // 800000
    float*          ed2    = (float*)(ecol + NE);                     // 800000

    // CSR build
    zero_kernel<<<64, 256, 0, stream>>>((float4*)deg, 50176 / 4);
    hist_kernel<<<NE / 256, 256, 0, stream>>>(ei, deg);
    scan1_kernel<<<NB1, 256, 0, stream>>>(deg, part, bsum);
    scan2_kernel<<<1, 256, 0, stream>>>(bsum, boff);
    scan3_kernel<<<197, 256, 0, stream>>>(part, boff, rowptr, cursor);
    scatter_kernel<<<NE / 256, 256, 0, stream>>>(ei, pos, cursor, ecol, ed2);

    // weight swizzles + x conversion
    wswz_kernel<<<(256 * D) / 256, 256, 0, stream>>>(W1e, w1f);
    wswz_kernel<<<(256 * D) / 256, 256, 0, stream>>>(W1n, w1nf);
    wswz_kernel<<<(D * D) / 256, 256, 0, stream>>>(W2e, w2f);
    wswz_kernel<<<(D * D) / 256, 256, 0, stream>>>(W2n, w2nf);
    wlf_kernel<<<1, 128, 0, stream>>>(W1e, wlf);
    x2bf_kernel<<<(NND * D / 4) / 256, 256, 0, stream>>>((const float4*)x, (uint2*)xbf);

    // A'/B precompute (MFMA)
    precompute_kernel<<<782, 256, 0, stream>>>(xbf, w1f, b1e, Abf, Bbf);

    // fused edge MLP + aggregation (1 wave = 1 node, pipelined)
    edgeagg_kernel<<<NND, 64, 0, stream>>>(Abf, Bbf, rowptr, ecol, ed2,
                                           wlf, w2f, b2e, aggbf);

    // node MLP + residual + LN (MFMA)
    node_kernel<<<NND / 16, 64, 0, stream>>>(xbf, aggbf, w1nf, b1n, w2nf, b2n,
                                             x, gamma, beta, out);
}

// Round 9
// 574.313 us; speedup vs baseline: 1.3731x; 1.3731x over previous
//
#include <hip/hip_runtime.h>
#include <hip/hip_bf16.h>
#include <math.h>

#define D 128
#define NND 50000
#define NE 800000
#define NB1 196        // scan blocks: 196*256 = 50176 >= 50000
#define TPITCH 152     // ushort pitch for node transpose tile (304 B = 19*16)

typedef __attribute__((ext_vector_type(8))) short shortx8;
typedef __attribute__((ext_vector_type(4))) float floatx4;

__device__ __forceinline__ float silu_f(float v) {
    return v / (1.0f + __expf(-v));
}
__device__ __forceinline__ unsigned short f2bf(float f) {
    union { float f; unsigned int u; } v; v.f = f;
    unsigned int u = v.u;
    u += 0x7fffu + ((u >> 16) & 1u);   // RNE
    return (unsigned short)(u >> 16);
}
__device__ __forceinline__ void unpk(unsigned int u, float& lo, float& hi) {
    union { unsigned int x; float f; } a, b;
    a.x = u << 16;
    b.x = u & 0xffff0000u;
    lo = a.f; hi = b.f;
}

// B-frag swizzle index mapping (shared by all weight preps):
// Wf[f] with f = (((ks*4+quad)*128)+n*16+mrow)*8+j  <->  W[k=ks*32+quad*8+j][col=n*16+mrow]
__device__ __forceinline__ void wswz_one(const float* __restrict__ W,
                                         unsigned short* __restrict__ Wf, int f) {
    int j    = f & 7;
    int mrow = (f >> 3) & 15;
    int n    = (f >> 7) & 7;
    int rest = f >> 10;
    int quad = rest & 3;
    int ks   = rest >> 2;
    int col = n * 16 + mrow;
    int k   = ks * 32 + quad * 8 + j;
    Wf[f] = f2bf(W[k * D + col]);
}

// ---------------- fused prep: x->bf16, 4 weight swizzles, wlf, zero deg -----
// 256 blocks x 256 threads, grid-stride everything. All sections independent.
__global__ __launch_bounds__(256) void prep_kernel(
        const float4* __restrict__ x4, uint2* __restrict__ xbf,
        const float* __restrict__ W1e, unsigned short* __restrict__ w1f,
        const float* __restrict__ W1n, unsigned short* __restrict__ w1nf,
        const float* __restrict__ W2e, unsigned short* __restrict__ w2f,
        const float* __restrict__ W2n, unsigned short* __restrict__ w2nf,
        unsigned short* __restrict__ wlf,
        int* __restrict__ deg) {
    const int gtid = blockIdx.x * 256 + threadIdx.x;   // 65536 threads
    const int gsz  = 65536;

    // x -> bf16 (1.6M float4 -> uint2)
    for (int i = gtid; i < NND * D / 4; i += gsz) {
        float4 v = x4[i];
        uint2 o;
        o.x = (unsigned int)f2bf(v.x) | ((unsigned int)f2bf(v.y) << 16);
        o.y = (unsigned int)f2bf(v.z) | ((unsigned int)f2bf(v.w) << 16);
        xbf[i] = o;
    }
    // weight swizzles
    for (int f = gtid; f < 256 * D; f += gsz) wswz_one(W1e, w1f, f);
    for (int f = gtid; f < 256 * D; f += gsz) wswz_one(W1n, w1nf, f);
    for (int f = gtid; f < D * D; f += gsz)   wswz_one(W2e, w2f, f);
    for (int f = gtid; f < D * D; f += gsz)   wswz_one(W2n, w2nf, f);
    // dist2 weight row, bf16 (k-order = lane chunk order)
    if (gtid < D) wlf[gtid] = f2bf(W1e[256 * D + gtid]);
    // zero degree histogram (50176 ints)
    for (int i = gtid; i < 50176; i += gsz) deg[i] = 0;
}

// ---------------- CSR build ----------------
__global__ __launch_bounds__(256) void hist_kernel(const int* __restrict__ ei,
                                                   int* __restrict__ deg) {
    const int gtid = blockIdx.x * 256 + threadIdx.x;   // 65536 threads
    for (int e = gtid; e < NE; e += 65536) atomicAdd(&deg[ei[e]], 1);
}

__global__ void scan1_kernel(const int* __restrict__ deg,
                             int* __restrict__ part, int* __restrict__ bsum) {
    __shared__ int s[256];
    const int tid = threadIdx.x;
    const int i = blockIdx.x * 256 + tid;
    int v = (i < NND) ? deg[i] : 0;
    s[tid] = v;
    __syncthreads();
    #pragma unroll
    for (int off = 1; off < 256; off <<= 1) {
        int t = (tid >= off) ? s[tid - off] : 0;
        __syncthreads();
        s[tid] += t;
        __syncthreads();
    }
    part[i] = s[tid] - v;                        // exclusive
    if (tid == 255) bsum[blockIdx.x] = s[255];
}

__global__ void scan2_kernel(const int* __restrict__ bsum, int* __restrict__ boff) {
    __shared__ int s[256];
    const int tid = threadIdx.x;
    int v = (tid < NB1) ? bsum[tid] : 0;
    s[tid] = v;
    __syncthreads();
    #pragma unroll
    for (int off = 1; off < 256; off <<= 1) {
        int t = (tid >= off) ? s[tid - off] : 0;
        __syncthreads();
        s[tid] += t;
        __syncthreads();
    }
    if (tid < NB1) boff[tid] = s[tid] - v;       // exclusive
}

__global__ void scan3_kernel(const int* __restrict__ part, const int* __restrict__ boff,
                             int* __restrict__ rowptr, int* __restrict__ cursor) {
    int i = blockIdx.x * 256 + threadIdx.x;
    if (i < NND) {
        int v = part[i] + boff[i >> 8];
        rowptr[i] = v;
        cursor[i] = v;
    } else if (i == NND) {
        rowptr[NND] = NE;
    }
}

__global__ __launch_bounds__(256) void scatter_kernel(
        const int* __restrict__ ei, const float* __restrict__ pos,
        int* __restrict__ cursor,
        int* __restrict__ ecol, float* __restrict__ ed2) {
    const int gtid = blockIdx.x * 256 + threadIdx.x;   // 65536 threads
    for (int e = gtid; e < NE; e += 65536) {
        int r = ei[e], c = ei[NE + e];
        float dx = pos[r * 3 + 0] - pos[c * 3 + 0];
        float dy = pos[r * 3 + 1] - pos[c * 3 + 1];
        float dz = pos[r * 3 + 2] - pos[c * 3 + 2];
        int slot = atomicAdd(&cursor[r], 1);
        ecol[slot] = c;
        ed2[slot] = dx * dx + dy * dy + dz * dz;
    }
}

// ---------------- A' = bf16(x@W1e_top + b1e), B = bf16(x@W1e_bot)  [MFMA] ----
// 256 blocks x 4 waves = 1024 waves, grid-stride over 3125 16-node tiles.
__global__ __launch_bounds__(256) void precompute_kernel(
        const unsigned short* __restrict__ xbf,
        const unsigned short* __restrict__ w1f,   // 256x128 swizzled
        const float* __restrict__ b1e,
        unsigned short* __restrict__ A,
        unsigned short* __restrict__ Bm) {
    const int t     = threadIdx.x;
    const int wv    = t >> 6;
    const int lane  = t & 63;
    const int mrow  = lane & 15;
    const int quad  = lane >> 4;
    const int gwave = blockIdx.x * 4 + wv;     // 1024 waves

    const uint4* wp = (const uint4*)w1f;
    float bb[8];
    #pragma unroll
    for (int n = 0; n < 8; ++n) bb[n] = b1e[n * 16 + mrow];

    for (int tile = gwave; tile < 3125; tile += 1024) {
        const int n0 = tile * 16;
        const uint4* xrow = (const uint4*)(xbf + ((size_t)(n0 + mrow) << 7));

        floatx4 accA[8], accB[8];
        #pragma unroll
        for (int n = 0; n < 8; ++n) {
            accA[n] = (floatx4){0.f, 0.f, 0.f, 0.f};
            accB[n] = (floatx4){0.f, 0.f, 0.f, 0.f};
        }

        #pragma unroll
        for (int s = 0; s < 4; ++s) {
            union { uint4 u; shortx8 v; } af;
            af.u = xrow[s * 4 + quad];
            const int baseA = (s * 4 + quad) * 128 + mrow;
            const int baseB = ((s + 4) * 4 + quad) * 128 + mrow;
            #pragma unroll
            for (int n = 0; n < 8; ++n) {
                union { uint4 u; shortx8 v; } bfA, bfB;
                bfA.u = wp[baseA + n * 16];
                bfB.u = wp[baseB + n * 16];
                accA[n] = __builtin_amdgcn_mfma_f32_16x16x32_bf16(af.v, bfA.v, accA[n], 0, 0, 0);
                accB[n] = __builtin_amdgcn_mfma_f32_16x16x32_bf16(af.v, bfB.v, accB[n], 0, 0, 0);
            }
        }

        #pragma unroll
        for (int reg = 0; reg < 4; ++reg) {
            const int node = n0 + quad * 4 + reg;
            #pragma unroll
            for (int n = 0; n < 8; ++n) {
                const int col = n * 16 + mrow;
                A[(size_t)node * D + col]  = f2bf(accA[n][reg] + bb[n]);
                Bm[(size_t)node * D + col] = f2bf(accB[n][reg]);
            }
        }
    }
}

// ---------------- fused edge MLP + per-node aggregation ----------------
// Persistent: 1024 blocks x 4 waves = 4096 waves, grid-stride over 50000 nodes.
// (R7 body; launch_bounds(256,2) is the proven no-spill config, VGPR=128.)
__global__ __launch_bounds__(256, 2) void edgeagg_kernel(
        const unsigned short* __restrict__ Abf,
        const unsigned short* __restrict__ Bbf,
        const int* __restrict__ rowptr,
        const int* __restrict__ ecol,
        const float* __restrict__ ed2,
        const unsigned short* __restrict__ wlf,
        const unsigned short* __restrict__ W2f,
        const float* __restrict__ b2e,
        unsigned short* __restrict__ aggbf) {
    const int t     = threadIdx.x;
    const int wv    = t >> 6;
    const int lane  = t & 63;
    const int mrow  = lane & 15;
    const int quad  = lane >> 4;
    const int gwave = blockIdx.x * 4 + wv;     // 4096 waves

    const uint4* w2p = (const uint4*)W2f;
    const uint4* wlq = (const uint4*)wlf;
    uint4 wlu[4];
    #pragma unroll
    for (int s = 0; s < 4; ++s) wlu[s] = wlq[s * 4 + quad];
    float bias[8];
    #pragma unroll
    for (int k = 0; k < 8; ++k) bias[k] = b2e[k * 16 + mrow];

    for (int node = gwave; node < NND; node += 4096) {
        const int start = rowptr[node];
        const int d     = rowptr[node + 1] - start;

        const uint4* arow = (const uint4*)(Abf + ((size_t)node << 7));
        uint4 au[4];
        #pragma unroll
        for (int s = 0; s < 4; ++s) au[s] = arow[s * 4 + quad];

        float nacc[8];
        #pragma unroll
        for (int k = 0; k < 8; ++k) nacc[k] = 0.f;

        for (int tb = 0; tb < d; tb += 16) {
            const int  ei16 = tb + mrow;
            const bool ve   = ei16 < d;
            const int  idx  = start + (ve ? ei16 : 0);
            const int  c    = ecol[idx];
            float d2        = ed2[idx];
            d2 = ve ? d2 : 0.f;
            const uint4* brow = (const uint4*)(Bbf + ((size_t)c << 7));

            floatx4 acc[8];
            #pragma unroll
            for (int k = 0; k < 8; ++k) acc[k] = (floatx4){0.f, 0.f, 0.f, 0.f};

            #pragma unroll
            for (int s = 0; s < 4; ++s) {
                uint4 bu = brow[s * 4 + quad];

                float a0, a1, a2, a3, a4, a5, a6, a7;
                float q0, q1, q2, q3, q4, q5, q6, q7;
                float w0, w1, w2, w3, w4, w5, w6, w7;
                unpk(au[s].x, a0, a1); unpk(au[s].y, a2, a3);
                unpk(au[s].z, a4, a5); unpk(au[s].w, a6, a7);
                unpk(bu.x, q0, q1); unpk(bu.y, q2, q3);
                unpk(bu.z, q4, q5); unpk(bu.w, q6, q7);
                unpk(wlu[s].x, w0, w1); unpk(wlu[s].y, w2, w3);
                unpk(wlu[s].z, w4, w5); unpk(wlu[s].w, w6, w7);

                float h0 = silu_f(fmaf(d2, w0, a0 + q0));
                float h1 = silu_f(fmaf(d2, w1, a1 + q1));
                float h2 = silu_f(fmaf(d2, w2, a2 + q2));
                float h3 = silu_f(fmaf(d2, w3, a3 + q3));
                float h4 = silu_f(fmaf(d2, w4, a4 + q4));
                float h5 = silu_f(fmaf(d2, w5, a5 + q5));
                float h6 = silu_f(fmaf(d2, w6, a6 + q6));
                float h7 = silu_f(fmaf(d2, w7, a7 + q7));

                union { shortx8 v; __hip_bfloat162 p[4]; } af;
                af.p[0] = __float22bfloat162_rn(float2{h0, h1});
                af.p[1] = __float22bfloat162_rn(float2{h2, h3});
                af.p[2] = __float22bfloat162_rn(float2{h4, h5});
                af.p[3] = __float22bfloat162_rn(float2{h6, h7});

                const int base = (s * 4 + quad) * 128 + mrow;
                #pragma unroll
                for (int k = 0; k < 8; ++k) {
                    union { uint4 u; shortx8 v; } bf;
                    bf.u = w2p[base + k * 16];
                    acc[k] = __builtin_amdgcn_mfma_f32_16x16x32_bf16(af.v, bf.v, acc[k], 0, 0, 0);
                }
            }

            #pragma unroll
            for (int reg = 0; reg < 4; ++reg) {
                const bool vr = (tb + quad * 4 + reg) < d;
                #pragma unroll
                for (int k = 0; k < 8; ++k)
                    nacc[k] += vr ? silu_f(acc[k][reg] + bias[k]) : 0.f;
            }
        }

        #pragma unroll
        for (int k = 0; k < 8; ++k) {
            float v = nacc[k];
            v += __shfl_xor(v, 16);
            v += __shfl_xor(v, 32);
            nacc[k] = v;
        }
        const int n8a = quad * 2, n8b = quad * 2 + 1;
        aggbf[(size_t)node * D + n8a * 16 + mrow] = f2bf(nacc[n8a]);
        aggbf[(size_t)node * D + n8b * 16 + mrow] = f2bf(nacc[n8b]);
    }
}

// ---------------- node MLP + residual + LayerNorm  [MFMA] ----------------
// Persistent: 1024 single-wave blocks, grid-stride over 3125 16-node tiles.
// (single wave per block -> uniform loop count -> __syncthreads inside loop is safe)
__global__ __launch_bounds__(64) void node_kernel(
        const unsigned short* __restrict__ xbf,
        const unsigned short* __restrict__ aggbf,
        const unsigned short* __restrict__ w1nf,  // 256x128 swizzled
        const float* __restrict__ b1n,
        const unsigned short* __restrict__ w2nf,  // 128x128 swizzled
        const float* __restrict__ b2n,
        const float* __restrict__ x,
        const float* __restrict__ gamma,
        const float* __restrict__ beta,
        float* __restrict__ out) {
    __shared__ __align__(16) unsigned short ts[16 * TPITCH];
    const int lane = threadIdx.x;
    const int mrow = lane & 15;
    const int quad = lane >> 4;

    const uint4* w1p = (const uint4*)w1nf;
    const uint4* w2p = (const uint4*)w2nf;

    float bb1[8], bb2[8], g[8], bt[8];
    #pragma unroll
    for (int n = 0; n < 8; ++n) {
        bb1[n] = b1n[n * 16 + mrow];
        bb2[n] = b2n[n * 16 + mrow];
        g[n]   = gamma[n * 16 + mrow];
        bt[n]  = beta[n * 16 + mrow];
    }

    for (int tile = blockIdx.x; tile < 3125; tile += 1024) {
        const int n0 = tile * 16;
        const uint4* xrow = (const uint4*)(xbf + ((size_t)(n0 + mrow) << 7));
        const uint4* grow = (const uint4*)(aggbf + ((size_t)(n0 + mrow) << 7));

        floatx4 acc[8];
        #pragma unroll
        for (int n = 0; n < 8; ++n)
            acc[n] = (floatx4){bb1[n], bb1[n], bb1[n], bb1[n]};

        #pragma unroll
        for (int s = 0; s < 4; ++s) {
            union { uint4 u; shortx8 v; } af;
            af.u = xrow[s * 4 + quad];
            const int base = (s * 4 + quad) * 128 + mrow;
            #pragma unroll
            for (int n = 0; n < 8; ++n) {
                union { uint4 u; shortx8 v; } bf;
                bf.u = w1p[base + n * 16];
                acc[n] = __builtin_amdgcn_mfma_f32_16x16x32_bf16(af.v, bf.v, acc[n], 0, 0, 0);
            }
        }
        #pragma unroll
        for (int s = 0; s < 4; ++s) {
            union { uint4 u; shortx8 v; } af;
            af.u = grow[s * 4 + quad];
            const int base = ((s + 4) * 4 + quad) * 128 + mrow;
            #pragma unroll
            for (int n = 0; n < 8; ++n) {
                union { uint4 u; shortx8 v; } bf;
                bf.u = w1p[base + n * 16];
                acc[n] = __builtin_amdgcn_mfma_f32_16x16x32_bf16(af.v, bf.v, acc[n], 0, 0, 0);
            }
        }

        // silu -> LDS (row-major [m][col], transpose for stage-2 A-frags)
        #pragma unroll
        for (int reg = 0; reg < 4; ++reg) {
            const int m = quad * 4 + reg;
            #pragma unroll
            for (int n = 0; n < 8; ++n)
                ts[m * TPITCH + n * 16 + mrow] = f2bf(silu_f(acc[n][reg]));
        }
        __syncthreads();   // single wave: cheap; orders LDS write->read

        floatx4 acc2[8];
        #pragma unroll
        for (int n = 0; n < 8; ++n)
            acc2[n] = (floatx4){bb2[n], bb2[n], bb2[n], bb2[n]};
        #pragma unroll
        for (int s = 0; s < 4; ++s) {
            shortx8 af2 = *(const shortx8*)((const char*)ts +
                            mrow * (TPITCH * 2) + (s * 4 + quad) * 16);
            const int base = (s * 4 + quad) * 128 + mrow;
            #pragma unroll
            for (int n = 0; n < 8; ++n) {
                union { uint4 u; shortx8 v; } bf;
                bf.u = w2p[base + n * 16];
                acc2[n] = __builtin_amdgcn_mfma_f32_16x16x32_bf16(af2, bf.v, acc2[n], 0, 0, 0);
            }
        }

        #pragma unroll
        for (int reg = 0; reg < 4; ++reg) {
            const int node = n0 + quad * 4 + reg;
            float u[8];
            float s1 = 0.f, s2 = 0.f;
            #pragma unroll
            for (int n = 0; n < 8; ++n) {
                u[n] = acc2[n][reg] + x[(size_t)node * D + n * 16 + mrow];
                s1 += u[n];
                s2 += u[n] * u[n];
            }
            #pragma unroll
            for (int off = 1; off < 16; off <<= 1) {
                s1 += __shfl_xor(s1, off);
                s2 += __shfl_xor(s2, off);
            }
            const float mu  = s1 * (1.f / 128.f);
            const float var = s2 * (1.f / 128.f) - mu * mu;
            const float rs  = rsqrtf(var + 1e-5f);
            #pragma unroll
            for (int n = 0; n < 8; ++n)
                out[(size_t)node * D + n * 16 + mrow] = (u[n] - mu) * rs * g[n] + bt[n];
        }
        __syncthreads();   // order stage-2 LDS reads before next iter's writes
    }
}

extern "C" void kernel_launch(void* const* d_in, const int* in_sizes, int n_in,
                              void* d_out, int out_size, void* d_ws, size_t ws_size,
                              hipStream_t stream) {
    const float* x     = (const float*)d_in[0];
    const float* pos   = (const float*)d_in[1];
    const int*   ei    = (const int*)d_in[2];
    const float* W1e   = (const float*)d_in[3];
    const float* b1e   = (const float*)d_in[4];
    const float* W2e   = (const float*)d_in[5];
    const float* b2e   = (const float*)d_in[6];
    const float* W1n   = (const float*)d_in[7];
    const float* b1n   = (const float*)d_in[8];
    const float* W2n   = (const float*)d_in[9];
    const float* b2n   = (const float*)d_in[10];
    const float* gamma = (const float*)d_in[11];
    const float* beta  = (const float*)d_in[12];
    float* out = (float*)d_out;

    // ws layout (all offsets 16B-aligned)
    unsigned short* Abf    = (unsigned short*)d_ws;                   // 12.8 MB
    unsigned short* Bbf    = Abf + (size_t)NND * D;                   // 12.8 MB
    unsigned short* aggbf  = Bbf + (size_t)NND * D;                   // 12.8 MB
    unsigned short* xbf    = aggbf + (size_t)NND * D;                 // 12.8 MB
    unsigned short* w1f    = xbf + (size_t)NND * D;                   // 64 KB (256x128)
    unsigned short* w1nf   = w1f + 256 * D;                           // 64 KB (256x128)
    unsigned short* w2f    = w1nf + 256 * D;                          // 32 KB (128x128)
    unsigned short* w2nf   = w2f + D * D;                             // 32 KB (128x128)
    unsigned short* wlf    = w2nf + D * D;                            // 256 B
    int*            deg    = (int*)(wlf + 128);                       // 50176
    int*            part   = deg + 50176;                             // 50176
    int*            bsum   = part + 50176;                            // 256
    int*            boff   = bsum + 256;                              // 256
    int*            rowptr = boff + 256;                              // 50004
    int*            cursor = rowptr + 50004;                          // 50000
    int*            ecol   = cursor + 50000;                          // 800000
    float*          ed2    = (float*)(ecol + NE);                     // 800000

    // K1: fused prep (x2bf + weight swizzles + wlf + zero deg)
    prep_kernel<<<256, 256, 0, stream>>>((const float4*)x, (uint2*)xbf,
                                         W1e, w1f, W1n, w1nf,
                                         W2e, w2f, W2n, w2nf, wlf, deg);
    // K2-K6: CSR build
    hist_kernel<<<256, 256, 0, stream>>>(ei, deg);
    scan1_kernel<<<NB1, 256, 0, stream>>>(deg, part, bsum);
    scan2_kernel<<<1, 256, 0, stream>>>(bsum, boff);
    scan3_kernel<<<197, 256, 0, stream>>>(part, boff, rowptr, cursor);
    scatter_kernel<<<256, 256, 0, stream>>>(ei, pos, cursor, ecol, ed2);

    // K7: A'/B precompute (MFMA, persistent)
    precompute_kernel<<<256, 256, 0, stream>>>(xbf, w1f, b1e, Abf, Bbf);

    // K8: fused edge MLP + aggregation (persistent, 4 waves/CU)
    edgeagg_kernel<<<1024, 256, 0, stream>>>(Abf, Bbf, rowptr, ecol, ed2,
                                             wlf, w2f, b2e, aggbf);

    // K9: node MLP + residual + LN (MFMA, persistent single-wave blocks)
    node_kernel<<<1024, 64, 0, stream>>>(xbf, aggbf, w1nf, b1n, w2nf, b2n,
                                         x, gamma, beta, out);
}